// Round 13
// baseline (522.763 us; speedup 1.0000x reference)
//
#include <hip/hip_runtime.h>
#include <stdint.h>

#define NROWS 16384
#define KDIM  512
#define BM 256
#define BN 128          // per-ct column strip
#define CT 4            // strips per block -> 512-col chunk
#define NCHUNK 32       // 16384 / 512
#define NPH 8           // K-tiles of 64: 512/64
#define SLOT 24576      // A 16KB + B 8KB (fp8)
#define INV_T 14.285714285714286f
#define LOG2E 1.4426950408889634f

typedef int   i32x4 __attribute__((ext_vector_type(4)));
typedef int   i32x8 __attribute__((ext_vector_type(8)));
typedef float f32x16 __attribute__((ext_vector_type(16)));

// async global->LDS, 16B/lane; LDS dest = wave-uniform base + lane*16
__device__ __forceinline__ void gload_lds16(const void* gptr, void* lptr) {
    uint32_t loff = (uint32_t)(uintptr_t)lptr;
    loff = __builtin_amdgcn_readfirstlane(loff);
    __builtin_amdgcn_global_load_lds(
        (const uint32_t __attribute__((address_space(1)))*)(uintptr_t)gptr,
        (uint32_t __attribute__((address_space(3)))*)(uintptr_t)loff,
        16, 0, 0);
}

// ---- fp8 e4m3 (OCP) encode: RNE-ish manual fallback ----
__device__ __forceinline__ uint32_t f2fp8_manual(float x) {
    uint32_t b = __float_as_uint(x);
    uint32_t s = (b >> 31) << 7;
    uint32_t mag = b & 0x7FFFFFFFu;
    if (mag >= 0x43E00000u) return s | 0x7Eu;          // clamp at 448 (never hit)
    if (mag < 0x3C000000u) {                            // < 2^-7 -> subnormal units 2^-9
        float m = __uint_as_float(mag) * 512.0f;
        return s | (uint32_t)(m + 0.5f);
    }
    uint32_t r = mag + 0x0007FFFFu + ((mag >> 20) & 1u);
    int e = (int)(r >> 23) - 120;                       // e4m3 exponent field
    uint32_t m3 = (r >> 20) & 7u;
    if (e <= 0) { float m = __uint_as_float(mag) * 512.0f; return s | (uint32_t)(m + 0.5f); }
    if (e > 15 || (e == 15 && m3 == 7)) return s | 0x7Eu;
    return s | ((uint32_t)e << 3) | m3;
}

__device__ __forceinline__ uint32_t pack4_fp8(float a, float b, float c, float d) {
#if __has_builtin(__builtin_amdgcn_cvt_pk_fp8_f32)
    int w = __builtin_amdgcn_cvt_pk_fp8_f32(a, b, 0, false);
    w = __builtin_amdgcn_cvt_pk_fp8_f32(c, d, w, true);
    return (uint32_t)w;
#else
    return f2fp8_manual(a) | (f2fp8_manual(b) << 8)
         | (f2fp8_manual(c) << 16) | (f2fp8_manual(d) << 24);
#endif
}

// FP8 fragment-major panel for mfma_scale_f32_32x32x64_f8f6f4:
// per (kt=k/64, rgrp=r/32): 2048B block at (kt*512+rgrp)*2048.
// MFMA lane l = kseg(l>>5)*32 + (r&31); lane's 32 k-bytes split:
//   g0 (k-in-seg 0-15) at half0 + lane*16 ; g1 (16-31) at 1024 + lane*16.
// Any within-K permutation identical in A and B panels cancels in the dot.

// ---- kernel 1: L2 normalize + scale + fp8 cast into fragment-major panel ----
__global__ void k_norm(const float* __restrict__ X, char* __restrict__ Y, float scale) {
    const int row  = blockIdx.x * 4 + (threadIdx.x >> 6);
    const int lane = threadIdx.x & 63;
    const float* xr = X + (size_t)row * KDIM + lane * 8;
    float4 a = *(const float4*)xr;
    float4 b = *(const float4*)(xr + 4);
    float ss = a.x*a.x + a.y*a.y + a.z*a.z + a.w*a.w
             + b.x*b.x + b.y*b.y + b.z*b.z + b.w*b.w;
    #pragma unroll
    for (int off = 1; off < 64; off <<= 1) ss += __shfl_xor(ss, off);
    const float s = scale / fmaxf(sqrtf(ss), 1e-12f);
    uint32_t w0 = pack4_fp8(a.x * s, a.y * s, a.z * s, a.w * s);
    uint32_t w1 = pack4_fp8(b.x * s, b.y * s, b.z * s, b.w * s);
    const int kt   = lane >> 3;             // k-tile of 64
    const int mlan = ((lane >> 2) & 1) * 32 + (row & 31);   // kseg*32 + r
    const int half = (lane >> 1) & 1;
    const int boff = (lane & 1) * 8;
    char* dst = Y + ((size_t)(kt * 512 + (row >> 5)) * 2048)
                  + half * 1024 + mlan * 16 + boff;
    *(uint32_t*)dst = w0;
    *(uint32_t*)(dst + 4) = w1;
}

// ---- kernel 2: fused MX-FP8 GEMM + exp2 + row-sum. 256x128/step, 8 waves (4Mx2N),
// 32x32x64 f8f6f4 (flat scales = 1.0), acc[2][2], ring-3 24KB slots (R9 ledger).
__global__ __launch_bounds__(512, 1) void k_gemm(const char* __restrict__ A,
                                                 const char* __restrict__ B,
                                                 float* __restrict__ S_part) {
    __shared__ __align__(16) char L[3 * SLOT];
    __shared__ float rowsum[2][BM];
    char* Lc = (char*)L;

    const int tid  = threadIdx.x;
    const int lane = tid & 63;
    const int w    = tid >> 6;           // 0..7
    const int wr   = w >> 1, wc = w & 1; // 4M x 2N; wave tile 64x64
    // XCD supertile swizzle (bijective, verified R9): 2048 blocks
    const int bid  = blockIdx.x;
    const int xcd  = bid & 7;
    const int idx  = bid >> 3;           // 0..255
    const int st   = idx >> 5;           // 0..7
    const int wsub = idx & 31;
    const int sg   = xcd * 8 + st;       // 0..63
    const int bg   = sg & 7, cg = sg >> 3;
    const int brow  = (bg * 8 + (wsub >> 2)) * BM;
    const int chunk = cg * 4 + (wsub & 3);    // 0..31
    const int rbA0 = brow >> 5;               // 8 rgrps of A

#define STGA(KT_, S_) do {                                                    \
        const char* g_ = A + ((size_t)((KT_) * 512 + rbA0) * 2048) + tid * 16;\
        char* l_ = Lc + (S_) * SLOT + tid * 16;                               \
        gload_lds16(g_,        l_);                                           \
        gload_lds16(g_ + 8192, l_ + 8192);                                    \
    } while (0)

#define STGB(KT_, S_) do {                                                    \
        const char* g_ = B + ((size_t)((KT_) * 512 + rbB0) * 2048) + tid * 16;\
        char* l_ = Lc + (S_) * SLOT + 16384 + tid * 16;                       \
        gload_lds16(g_, l_);                                                  \
    } while (0)

// read frags of K-tile HH_ from slot (HH_%3)
#define RDS(HH_) do {                                                         \
        const char* sl_ = Lc + ((HH_) % 3) * SLOT;                            \
        _Pragma("unroll") for (int m_ = 0; m_ < 2; ++m_) {                    \
            i32x4 lo_ = *(const i32x4*)(sl_ + ((wr * 2 + m_) << 11) + (lane << 4));       \
            i32x4 hi_ = *(const i32x4*)(sl_ + ((wr * 2 + m_) << 11) + 1024 + (lane << 4));\
            _Pragma("unroll") for (int j_ = 0; j_ < 4; ++j_) {                \
                aI[m_][j_] = lo_[j_]; aI[m_][4 + j_] = hi_[j_]; }             \
        }                                                                     \
        _Pragma("unroll") for (int n_ = 0; n_ < 2; ++n_) {                    \
            i32x4 lo_ = *(const i32x4*)(sl_ + 16384 + ((wc * 2 + n_) << 11) + (lane << 4));       \
            i32x4 hi_ = *(const i32x4*)(sl_ + 16384 + ((wc * 2 + n_) << 11) + 1024 + (lane << 4));\
            _Pragma("unroll") for (int j_ = 0; j_ < 4; ++j_) {                \
                bI[n_][j_] = lo_[j_]; bI[n_][4 + j_] = hi_[j_]; }             \
        }                                                                     \
    } while (0)

#define MM() do {                                                             \
        __builtin_amdgcn_s_setprio(1);                                        \
        _Pragma("unroll") for (int m_ = 0; m_ < 2; ++m_)                      \
        _Pragma("unroll") for (int n_ = 0; n_ < 2; ++n_)                      \
            acc[m_][n_] = __builtin_amdgcn_mfma_scale_f32_32x32x64_f8f6f4(    \
                aI[m_], bI[n_], acc[m_][n_], 0, 0,                            \
                0, 0x7F7F7F7F, 0, 0x7F7F7F7F);                                \
        __builtin_amdgcn_s_setprio(0);                                        \
    } while (0)

    float rowacc = 0.f;
    #pragma unroll 1
    for (int ct = 0; ct < CT; ++ct) {
        const int rbB0 = chunk * 16 + ct * 4;   // 4 rgrps of B (128 cols)
        f32x16 acc[2][2] = {};
        i32x8 aI[2], bI[2];

        // prologue: stage T0->slot0, T1->slot1 (3 loads each); wait T0
        STGA(0, 0); STGB(0, 0);
        STGA(1, 1); STGB(1, 1);
        asm volatile("s_waitcnt vmcnt(3)" ::: "memory");
        __builtin_amdgcn_s_barrier();

        #pragma unroll
        for (int h = 0; h < NPH; ++h) {
            RDS(h);
            if (h < NPH - 2) { STGA(h + 2, (h + 2) % 3); STGB(h + 2, (h + 2) % 3); }
            MM();
            if (h < NPH - 2)       asm volatile("s_waitcnt vmcnt(3)" ::: "memory");
            else if (h == NPH - 2) asm volatile("s_waitcnt vmcnt(0)" ::: "memory");
            __builtin_amdgcn_s_barrier();
        }

        // epilogue: C/D 32x32: col=lane&31, row=(r&3)+8*(r>>2)+4*(lane>>5)
        #pragma unroll
        for (int m = 0; m < 2; ++m) {
            float rs[16];
            #pragma unroll
            for (int r = 0; r < 16; ++r)
                rs[r] = __builtin_amdgcn_exp2f(acc[m][0][r])
                      + __builtin_amdgcn_exp2f(acc[m][1][r]);
            #pragma unroll
            for (int off = 16; off >= 1; off >>= 1)
                #pragma unroll
                for (int r = 0; r < 16; ++r)
                    rs[r] += __shfl_xor(rs[r], off);
            if ((lane & 31) == 0) {
                const int rb = wr * 64 + m * 32 + (lane >> 5) * 4;
                #pragma unroll
                for (int r = 0; r < 16; ++r)
                    rowsum[wc][rb + (r & 3) + 8 * (r >> 2)] = rs[r];
            }
        }
        __syncthreads();
        if (tid < BM) rowacc += rowsum[0][tid] + rowsum[1][tid];
        __syncthreads();
    }
#undef STGA
#undef STGB
#undef RDS
#undef MM
    if (tid < BM) S_part[(size_t)chunk * NROWS + brow + tid] = rowacc;
}

// ---- kernel 3: diagonal logits in fp32 from RAW inputs (natural 1/T units) ----
__global__ void k_diag(const float* __restrict__ X1, const float* __restrict__ X2,
                       float* __restrict__ diag) {
    const int row  = blockIdx.x * 4 + (threadIdx.x >> 6);
    const int lane = threadIdx.x & 63;
    const float* x1 = X1 + (size_t)row * KDIM + lane * 8;
    const float* x2 = X2 + (size_t)row * KDIM + lane * 8;
    float4 a0 = *(const float4*)x1, a1 = *(const float4*)(x1 + 4);
    float4 b0 = *(const float4*)x2, b1 = *(const float4*)(x2 + 4);
    float s1 = a0.x*a0.x + a0.y*a0.y + a0.z*a0.z + a0.w*a0.w
             + a1.x*a1.x + a1.y*a1.y + a1.z*a1.z + a1.w*a1.w;
    float s2 = b0.x*b0.x + b0.y*b0.y + b0.z*b0.z + b0.w*b0.w
             + b1.x*b1.x + b1.y*b1.y + b1.z*b1.z + b1.w*b1.w;
    float dd = a0.x*b0.x + a0.y*b0.y + a0.z*b0.z + a0.w*b0.w
             + a1.x*b1.x + a1.y*b1.y + a1.z*b1.z + a1.w*b1.w;
    #pragma unroll
    for (int off = 1; off < 64; off <<= 1) {
        s1 += __shfl_xor(s1, off);
        s2 += __shfl_xor(s2, off);
        dd += __shfl_xor(dd, off);
    }
    if (lane == 0)
        diag[row] = dd / (fmaxf(sqrtf(s1), 1e-12f) * fmaxf(sqrtf(s2), 1e-12f)) * INV_T;
}

// ---- kernel 4: per-row loss + deterministic block partials ----
__global__ void k_loss(const float* __restrict__ S_part, const float* __restrict__ diag,
                       float* __restrict__ partial) {
    const int g = blockIdx.x * 256 + threadIdx.x;
    float S = 0.f;
    #pragma unroll
    for (int c = 0; c < NCHUNK; ++c) S += S_part[(size_t)c * NROWS + g];
    float v = logf(S) - diag[g];
    __shared__ float wsum[4];
    #pragma unroll
    for (int off = 1; off < 64; off <<= 1) v += __shfl_xor(v, off);
    if ((threadIdx.x & 63) == 0) wsum[threadIdx.x >> 6] = v;
    __syncthreads();
    if (threadIdx.x == 0) partial[blockIdx.x] = wsum[0] + wsum[1] + wsum[2] + wsum[3];
}

__global__ void k_final(const float* __restrict__ partial, float* __restrict__ out) {
    float v = partial[threadIdx.x];
    #pragma unroll
    for (int off = 1; off < 64; off <<= 1) v += __shfl_xor(v, off);
    if (threadIdx.x == 0) out[0] = v * (1.0f / (float)NROWS);
}

extern "C" void kernel_launch(void* const* d_in, const int* in_sizes, int n_in,
                              void* d_out, int out_size, void* d_ws, size_t ws_size,
                              hipStream_t stream) {
    const float* f1 = (const float*)d_in[0];
    const float* f2 = (const float*)d_in[1];
    float* out = (float*)d_out;

    char* ws = (char*)d_ws;
    char*  f1p   = ws;                                  // 8 MB fp8 panel
    char*  f2p   = ws + (16u << 20);                    // 8 MB fp8 panel
    float* S_part = (float*)(ws + (32u << 20));         // 2 MB [NCHUNK][NROWS]
    float* diag   = (float*)(ws + (34u << 20));         // 64 KB
    float* part   = (float*)(ws + (34u << 20) + (1u << 16)); // 256 B

    k_norm<<<dim3(NROWS / 4), dim3(256), 0, stream>>>(f1, f1p, INV_T * LOG2E);
    k_norm<<<dim3(NROWS / 4), dim3(256), 0, stream>>>(f2, f2p, 1.0f);
    k_gemm<<<dim3((NROWS / BM) * NCHUNK), dim3(512), 0, stream>>>(f1p, f2p, S_part);
    k_diag<<<dim3(NROWS / 4), dim3(256), 0, stream>>>(f1, f2, diag);
    k_loss<<<dim3(NROWS / 256), dim3(256), 0, stream>>>(S_part, diag, part);
    k_final<<<dim3(1), dim3(64), 0, stream>>>(part, out);
}

// Round 14
// 476.765 us; speedup vs baseline: 1.0965x; 1.0965x over previous
//
#include <hip/hip_runtime.h>
#include <stdint.h>

#define NROWS 16384
#define KDIM  512
#define BM 256
#define BN 256
#define CT 2
#define NCHUNK 32       // 16384 / (BN*CT)
#define INV_T 14.285714285714286f
#define LOG2E 1.4426950408889634f
#define LN2   0.6931471805599453f

typedef __bf16 bf16x8 __attribute__((ext_vector_type(8)));
typedef float  f32x4  __attribute__((ext_vector_type(4)));
typedef unsigned short u16x8 __attribute__((ext_vector_type(8)));

// async global->LDS, 16B/lane; LDS dest = wave-uniform base + lane*16
__device__ __forceinline__ void gload_lds16(const void* gptr, void* lptr) {
    uint32_t loff = (uint32_t)(uintptr_t)lptr;
    loff = __builtin_amdgcn_readfirstlane(loff);
    __builtin_amdgcn_global_load_lds(
        (const uint32_t __attribute__((address_space(1)))*)(uintptr_t)gptr,
        (uint32_t __attribute__((address_space(3)))*)(uintptr_t)loff,
        16, 0, 0);
}

// Fragment-major panel for mfma_16x16x32_bf16 (R7-verified exact):
// granule(row r, octet ko=k/8) at idx = (kt*64 + rb)*2048 + (mf*2+ksub)*64 + oo*16 + r16
//   kt=ko>>3, ksub=(ko>>2)&1, oo=ko&3, rb=r>>8, mf=(r>>4)&15, r16=r&15.
// One K-tile x 256-row chunk = 2048 granules = 32KB contiguous.
// MFMA lane l (row=l&15, octet=l>>4) reads granule base+l: lane-contiguous, conflict-free.

// ---- kernel 1: L2 normalize + scale + bf16 cast into fragment-major panel ----
__global__ void k_norm(const float* __restrict__ X, char* __restrict__ Y, float scale) {
    const int row  = blockIdx.x * 4 + (threadIdx.x >> 6);
    const int lane = threadIdx.x & 63;      // lane = k-octet ko
    const float* xr = X + (size_t)row * KDIM + lane * 8;
    float4 a = *(const float4*)xr;
    float4 b = *(const float4*)(xr + 4);
    float ss = a.x*a.x + a.y*a.y + a.z*a.z + a.w*a.w
             + b.x*b.x + b.y*b.y + b.z*b.z + b.w*b.w;
    #pragma unroll
    for (int off = 1; off < 64; off <<= 1) ss += __shfl_xor(ss, off);
    const float s = scale / fmaxf(sqrtf(ss), 1e-12f);
    __bf16 o[8];
    o[0] = (__bf16)(a.x * s); o[1] = (__bf16)(a.y * s);
    o[2] = (__bf16)(a.z * s); o[3] = (__bf16)(a.w * s);
    o[4] = (__bf16)(b.x * s); o[5] = (__bf16)(b.y * s);
    o[6] = (__bf16)(b.z * s); o[7] = (__bf16)(b.w * s);
    const int kt = lane >> 3, ksub = (lane >> 2) & 1, oo = lane & 3;
    const size_t gr = ((size_t)(kt * 64 + (row >> 8)) * 2048)
                    + ((((row >> 4) & 15) * 2 + ksub) * 64) + oo * 16 + (row & 15);
    *(u16x8*)(Y + gr * 16) = *(const u16x8*)o;
}

// ---- kernel 2: fused GEMM + exp2 + row-sum. 256x256 tile, 8 waves (2Mx4N),
// 16x16x32 MFMA, 8-phase quadrant schedule, double-buffered 64KB K-tile bufs.
// launch_bounds(512,1): budget 256 regs/wave -> acc(128 AGPR)+frags fit, no spill.
__global__ __launch_bounds__(512, 1) void k_gemm(const char* __restrict__ A,
                                                 const char* __restrict__ B,
                                                 float* __restrict__ S_part) {
    __shared__ __align__(16) char L[2 * 65536];   // buf{0,1}: A 32KB + B 32KB
    __shared__ float rowsum[4][BM];
    char* Lc = (char*)L;

    const int tid  = threadIdx.x;
    const int lane = tid & 63;
    const int w    = tid >> 6;           // 0..7
    const int wr   = w >> 2, wc = w & 3; // 2M x 4N wave grid; wave tile 128x64
    // XCD supertile swizzle: per XCD 8 supertiles of (8 brow x 4 chunk)
    const int bid  = blockIdx.x;
    const int xcd  = bid & 7;
    const int idx  = bid >> 3;
    const int st   = idx >> 5;
    const int wsub = idx & 31;
    const int brow  = (st * 8 + (wsub >> 2)) * BM;
    const int chunk = xcd * 4 + (wsub & 3);   // 0..31
    const int rbA = brow >> 8;

// stage one 32KB (kt, rowblk) chunk linearly: 4 x 8KB, per call tid*16 (lane-exact)
#define STG(P_, RB_, KT_, LB_) do {                                           \
        const char* g_ = (P_) + ((size_t)((KT_) * 64 + (RB_)) * 32768) + tid * 16; \
        char* l_ = Lc + (LB_) + tid * 16;                                     \
        gload_lds16(g_,         l_);                                          \
        gload_lds16(g_ +  8192, l_ +  8192);                                  \
        gload_lds16(g_ + 16384, l_ + 16384);                                  \
        gload_lds16(g_ + 24576, l_ + 24576);                                  \
    } while (0)

#define RD_A4(MLO_, BUFB_) do {                                               \
        _Pragma("unroll") for (int m_ = 0; m_ < 4; ++m_)                      \
        _Pragma("unroll") for (int ks_ = 0; ks_ < 2; ++ks_)                   \
            a[m_][ks_] = *(const bf16x8*)(Lc + (BUFB_)                        \
                + (((wr * 8 + (MLO_) + m_) * 2 + ks_) << 10) + (lane << 4));  \
    } while (0)

#define RD_B2(NLO_, BUFB_) do {                                               \
        _Pragma("unroll") for (int n_ = 0; n_ < 2; ++n_)                      \
        _Pragma("unroll") for (int ks_ = 0; ks_ < 2; ++ks_)                   \
            b[n_][ks_] = *(const bf16x8*)(Lc + (BUFB_) + 32768                \
                + (((wc * 4 + (NLO_) + n_) * 2 + ks_) << 10) + (lane << 4));  \
    } while (0)

#define MM8(MLO_, NLO_) do {                                                  \
        __builtin_amdgcn_s_setprio(1);                                        \
        _Pragma("unroll") for (int m_ = 0; m_ < 4; ++m_)                      \
        _Pragma("unroll") for (int n_ = 0; n_ < 2; ++n_)                      \
        _Pragma("unroll") for (int ks_ = 0; ks_ < 2; ++ks_)                   \
            acc[(MLO_) + m_][(NLO_) + n_] =                                   \
                __builtin_amdgcn_mfma_f32_16x16x32_bf16(                      \
                    a[m_][ks_], b[n_][ks_], acc[(MLO_) + m_][(NLO_) + n_],    \
                    0, 0, 0);                                                 \
        __builtin_amdgcn_s_setprio(0);                                        \
    } while (0)

#define BAR_LGKM() do {                                                       \
        __builtin_amdgcn_s_barrier();                                         \
        asm volatile("s_waitcnt lgkmcnt(0)" ::: "memory");                    \
        __builtin_amdgcn_sched_barrier(0);                                    \
    } while (0)

    float rowacc = 0.f;
    for (int ct = 0; ct < CT; ++ct) {
        const int rbB = chunk * CT + ct;     // B panel rowblk (cols/256)
        f32x4 acc[8][4] = {};
        bf16x8 a[4][2], b[2][2];

        // prologue: stage kt0 -> buf0, kt1 -> buf1 (8 loads each); wait kt0
        STG(A, rbA, 0, 0);
        STG(B, rbB, 0, 32768);
        STG(A, rbA, 1, 65536);
        STG(B, rbB, 1, 98304);
        asm volatile("s_waitcnt vmcnt(8)" ::: "memory");
        __builtin_amdgcn_s_barrier();

        #pragma unroll
        for (int i = 0; i < 4; ++i) {
            // ---- K-tile 2i (buf0) ----
            // ph1: quadrant (m0-3 x n0-1); stage buf1's next A (kt 2i+1, i>0)
            RD_A4(0, 0); RD_B2(0, 0);
            if (i > 0) STG(A, rbA, 2 * i + 1, 65536);
            asm volatile("s_waitcnt lgkmcnt(8)" ::: "memory");
            BAR_LGKM(); MM8(0, 0); __builtin_amdgcn_s_barrier();
            // ph2: (m0-3 x n2-3); stage buf1's next B
            RD_B2(2, 0);
            if (i > 0) STG(B, rbB, 2 * i + 1, 98304);
            BAR_LGKM(); MM8(0, 2); __builtin_amdgcn_s_barrier();
            // ph3: (m4-7 x n2-3)
            RD_A4(4, 0);
            BAR_LGKM(); MM8(4, 2); __builtin_amdgcn_s_barrier();
            // ph4: (m4-7 x n0-1); buf1 content (kt 2i+1) must be landed
            RD_B2(0, 0);
            asm volatile("s_waitcnt vmcnt(0)" ::: "memory");
            BAR_LGKM(); MM8(4, 0); __builtin_amdgcn_s_barrier();
            // ---- K-tile 2i+1 (buf1) ----
            // ph5: stage buf0's next A (kt 2i+2, i<3)
            RD_A4(0, 65536); RD_B2(0, 65536);
            if (i < 3) STG(A, rbA, 2 * i + 2, 0);
            asm volatile("s_waitcnt lgkmcnt(8)" ::: "memory");
            BAR_LGKM(); MM8(0, 0); __builtin_amdgcn_s_barrier();
            // ph6: stage buf0's next B
            RD_B2(2, 65536);
            if (i < 3) STG(B, rbB, 2 * i + 2, 32768);
            BAR_LGKM(); MM8(0, 2); __builtin_amdgcn_s_barrier();
            // ph7
            RD_A4(4, 65536);
            BAR_LGKM(); MM8(4, 2); __builtin_amdgcn_s_barrier();
            // ph8: buf0 content (kt 2i+2) must be landed before next iter ph1
            RD_B2(0, 65536);
            if (i < 3) asm volatile("s_waitcnt vmcnt(0)" ::: "memory");
            BAR_LGKM(); MM8(4, 0); __builtin_amdgcn_s_barrier();
        }

        // epilogue: exp2 + row-reduce. C/D: row=(lane>>4)*4+r, col=lane&15
        #pragma unroll
        for (int m = 0; m < 8; ++m) {
            float rs[4];
            #pragma unroll
            for (int r = 0; r < 4; ++r)
                rs[r] = __builtin_amdgcn_exp2f(acc[m][0][r])
                      + __builtin_amdgcn_exp2f(acc[m][1][r])
                      + __builtin_amdgcn_exp2f(acc[m][2][r])
                      + __builtin_amdgcn_exp2f(acc[m][3][r]);
            #pragma unroll
            for (int off = 8; off >= 1; off >>= 1)
                #pragma unroll
                for (int r = 0; r < 4; ++r)
                    rs[r] += __shfl_xor(rs[r], off);
            if ((lane & 15) == 0) {
                #pragma unroll
                for (int r = 0; r < 4; ++r)
                    rowsum[wc][wr * 128 + m * 16 + (lane >> 4) * 4 + r] = rs[r];
            }
        }
        __syncthreads();
        if (tid < BM)
            rowacc += rowsum[0][tid] + rowsum[1][tid] + rowsum[2][tid] + rowsum[3][tid];
        __syncthreads();
    }
#undef STG
#undef RD_A4
#undef RD_B2
#undef MM8
#undef BAR_LGKM
    if (tid < BM) S_part[(size_t)chunk * NROWS + brow + tid] = rowacc;
}

// ---- kernel 3: diagonal logits (log2-scaled), fragment-major panel ----
__global__ void k_diag(const char* __restrict__ A, const char* __restrict__ B,
                       float* __restrict__ diag) {
    const int row  = blockIdx.x * 4 + (threadIdx.x >> 6);
    const int lane = threadIdx.x & 63;
    const int kt = lane >> 3, ksub = (lane >> 2) & 1, oo = lane & 3;
    const size_t gr = ((size_t)(kt * 64 + (row >> 8)) * 2048)
                    + ((((row >> 4) & 15) * 2 + ksub) * 64) + oo * 16 + (row & 15);
    const bf16x8 va = *(const bf16x8*)(A + gr * 16);
    const bf16x8 vb = *(const bf16x8*)(B + gr * 16);
    float d = 0.f;
    #pragma unroll
    for (int i = 0; i < 8; ++i) d += (float)va[i] * (float)vb[i];
    #pragma unroll
    for (int off2 = 1; off2 < 64; off2 <<= 1) d += __shfl_xor(d, off2);
    if (lane == 0) diag[row] = d;
}

// ---- kernel 4: per-row loss + deterministic block partials ----
__global__ void k_loss(const float* __restrict__ S_part, const float* __restrict__ diag,
                       float* __restrict__ partial) {
    const int g = blockIdx.x * 256 + threadIdx.x;
    float S = 0.f;
    #pragma unroll
    for (int c = 0; c < NCHUNK; ++c) S += S_part[(size_t)c * NROWS + g];
    float v = logf(S) - diag[g] * LN2;   // diag is log2-scaled
    __shared__ float wsum[4];
    #pragma unroll
    for (int off = 1; off < 64; off <<= 1) v += __shfl_xor(v, off);
    if ((threadIdx.x & 63) == 0) wsum[threadIdx.x >> 6] = v;
    __syncthreads();
    if (threadIdx.x == 0) partial[blockIdx.x] = wsum[0] + wsum[1] + wsum[2] + wsum[3];
}

__global__ void k_final(const float* __restrict__ partial, float* __restrict__ out) {
    float v = partial[threadIdx.x];
    #pragma unroll
    for (int off = 1; off < 64; off <<= 1) v += __shfl_xor(v, off);
    if (threadIdx.x == 0) out[0] = v * (1.0f / (float)NROWS);
}

extern "C" void kernel_launch(void* const* d_in, const int* in_sizes, int n_in,
                              void* d_out, int out_size, void* d_ws, size_t ws_size,
                              hipStream_t stream) {
    const float* f1 = (const float*)d_in[0];
    const float* f2 = (const float*)d_in[1];
    float* out = (float*)d_out;

    char* ws = (char*)d_ws;
    char*  f1p   = ws;                                  // 16 MB panel
    char*  f2p   = ws + (16u << 20);                    // 16 MB panel
    float* S_part = (float*)(ws + (32u << 20));         // 2 MB [NCHUNK][NROWS]
    float* diag   = (float*)(ws + (34u << 20));         // 64 KB
    float* part   = (float*)(ws + (34u << 20) + (1u << 16)); // 256 B

    k_norm<<<dim3(NROWS / 4), dim3(256), 0, stream>>>(f1, f1p, INV_T * LOG2E);
    k_norm<<<dim3(NROWS / 4), dim3(256), 0, stream>>>(f2, f2p, 1.0f);
    k_gemm<<<dim3((NROWS / BM) * NCHUNK), dim3(512), 0, stream>>>(f1p, f2p, S_part);
    k_diag<<<dim3(NROWS / 4), dim3(256), 0, stream>>>(f1p, f2p, diag);
    k_loss<<<dim3(NROWS / 256), dim3(256), 0, stream>>>(S_part, diag, part);
    k_final<<<dim3(1), dim3(64), 0, stream>>>(part, out);
}